// Round 5
// baseline (602.038 us; speedup 1.0000x reference)
//
#include <hip/hip_runtime.h>

typedef unsigned short u16;
typedef unsigned int u32;
typedef __attribute__((ext_vector_type(8))) short bf16x8;
typedef __attribute__((ext_vector_type(4))) float f32x4;

#define LDK 72   // A-tile LDS stride (64 + 8 pad)

__device__ __forceinline__ u16 f2bf(float f) {
    u32 u = __float_as_uint(f);
    u += 0x7fffu + ((u >> 16) & 1u);   // round-to-nearest-even
    return (u16)(u >> 16);
}

__device__ __forceinline__ f32x4 mfma16(bf16x8 a, bf16x8 b, f32x4 c) {
    return __builtin_amdgcn_mfma_f32_16x16x32_bf16(a, b, c, 0, 0, 0);
}

// ---------------- prep: fold numeric features (split-k x8) ----------------

__global__ __launch_bounds__(256) void prep_u_kernel(
    const float* __restrict__ w_num, const float* __restrict__ b_num,
    const float* __restrict__ W_first, float* __restrict__ Upart, float* __restrict__ Ppart)
{
    __shared__ float wrow[32];
    __shared__ float brow[32];
    int j = threadIdx.x, f = blockIdx.x, ks = blockIdx.y;
    if (j < 32) {
        wrow[j] = w_num[f * 256 + ks * 32 + j];
        brow[j] = b_num[f * 256 + ks * 32 + j];
    }
    __syncthreads();
    float au = 0.f, ap = 0.f;
#pragma unroll 8
    for (int k = 0; k < 32; k++) {
        float w = W_first[(size_t)((f << 8) + ks * 32 + k) * 256 + j];
        au = fmaf(wrow[k], w, au);
        ap = fmaf(brow[k], w, ap);
    }
    Upart[(size_t)(ks * 32 + f) * 256 + j] = au;
    Ppart[(size_t)(ks * 32 + f) * 256 + j] = ap;
}

__global__ __launch_bounds__(256) void prep_reduce_kernel(
    const float* __restrict__ Upart, const float* __restrict__ Ppart,
    float* __restrict__ U, float* __restrict__ P)
{
    int j = threadIdx.x, f = blockIdx.x;
    float au = 0.f, ap = 0.f;
#pragma unroll
    for (int ks = 0; ks < 8; ks++) {
        au += Upart[(size_t)(ks * 32 + f) * 256 + j];
        ap += Ppart[(size_t)(ks * 32 + f) * 256 + j];
    }
    U[f * 256 + j] = au;
    P[f * 256 + j] = ap;
}

// ---------------- prep: LDS-tiled transpose f32 -> bf16 ----------------
__global__ __launch_bounds__(256) void transpose_kernel(
    const float* __restrict__ in, u16* __restrict__ out,
    int R, int C, int ldo, int k_off, size_t in_stride, size_t out_stride)
{
    __shared__ float t[64][65];
    in  += (size_t)blockIdx.z * in_stride;
    out += (size_t)blockIdx.z * out_stride;
    const int tid = threadIdx.x;
    const int r0 = blockIdx.x * 64, c0 = blockIdx.y * 64;
#pragma unroll
    for (int i = 0; i < 16; i++) {
        int e = tid + i * 256;
        int r = e >> 6, c = e & 63;
        float v = (r0 + r < R) ? in[(size_t)(r0 + r) * C + c0 + c] : 0.f;
        t[c][r] = v;
    }
    __syncthreads();
#pragma unroll
    for (int i = 0; i < 2; i++) {
        int e = tid + i * 256;
        int c = e >> 3, r8 = (e & 7) * 8;
        u16 tmp[8];
#pragma unroll
        for (int x = 0; x < 8; x++) tmp[x] = f2bf(t[c][r8 + x]);
        *(bf16x8*)&out[(size_t)(c0 + c) * ldo + k_off + r0 + r8] = *(bf16x8*)tmp;
    }
}

// ---------------- first layer: gathered-A GEMM ----------------
#define FBM 64

#define GATHER(KQ, G0, G1)                                                    \
    {                                                                         \
        int chunk = tid;                                                      \
        int r = chunk >> 4, c4 = chunk & 15;                                  \
        int k = (KQ) + c4 * 4;                                                \
        int rowi = (k < 4096) ? sidx[r * 16 + ((k >> 8) & 15)] : 0;           \
        G0 = *(const float4*)&cemb[(size_t)rowi * 256 + (k & 255)];           \
        if (k >= 4096) {                                                      \
            if (k < 4128) {                                                   \
                int c = r * 32 + (k - 4096);                                  \
                G0.x = sx[c]; G0.y = sx[c + 1];                               \
                G0.z = sx[c + 2]; G0.w = sx[c + 3];                           \
            } else G0 = make_float4(0.f, 0.f, 0.f, 0.f);                      \
        }                                                                     \
        chunk = tid + 512;                                                    \
        r = chunk >> 4; c4 = chunk & 15;                                      \
        k = (KQ) + c4 * 4;                                                    \
        rowi = (k < 4096) ? sidx[r * 16 + ((k >> 8) & 15)] : 0;               \
        G1 = *(const float4*)&cemb[(size_t)rowi * 256 + (k & 255)];           \
        if (k >= 4096) {                                                      \
            if (k < 4128) {                                                   \
                int c = r * 32 + (k - 4096);                                  \
                G1.x = sx[c]; G1.y = sx[c + 1];                               \
                G1.z = sx[c + 2]; G1.w = sx[c + 3];                           \
            } else G1 = make_float4(0.f, 0.f, 0.f, 0.f);                      \
        }                                                                     \
    }

#define WRITE_A(BUF, G0, G1)                                                  \
    {                                                                         \
        int chunk = tid;                                                      \
        int r = chunk >> 4, c4 = chunk & 15;                                  \
        ushort4 o;                                                            \
        o.x = f2bf(G0.x); o.y = f2bf(G0.y); o.z = f2bf(G0.z); o.w = f2bf(G0.w); \
        *(ushort4*)&Ab[BUF][r * LDK + c4 * 4] = o;                            \
        chunk = tid + 512;                                                    \
        r = chunk >> 4; c4 = chunk & 15;                                      \
        o.x = f2bf(G1.x); o.y = f2bf(G1.y); o.z = f2bf(G1.z); o.w = f2bf(G1.w); \
        *(ushort4*)&Ab[BUF][r * LDK + c4 * 4] = o;                            \
    }

#define DMA_B(BUF, KQ)                                                        \
    _Pragma("unroll")                                                         \
    for (int it = 0; it < 4; it++) {                                          \
        int chunk = it * 512 + tid;                                           \
        int r = chunk >> 3;                                                   \
        int c8 = (chunk & 7) ^ (r & 7);                                       \
        const u16* src = &BT[(size_t)r * 4160 + (KQ) + c8 * 8];               \
        __builtin_amdgcn_global_load_lds(                                     \
            (const __attribute__((address_space(1))) void*)src,               \
            (__attribute__((address_space(3))) void*)&Bb[BUF][(it * 512 + wv * 64) * 8], \
            16, 0, 0);                                                        \
    }

#define COMPUTE(AB, BB)                                                       \
    _Pragma("unroll")                                                         \
    for (int kk = 0; kk < 64; kk += 32) {                                     \
        bf16x8 af[2], bfr[4];                                                 \
        _Pragma("unroll")                                                     \
        for (int i = 0; i < 2; i++)                                           \
            af[i] = *(const bf16x8*)&Ab[AB][(wm * 32 + i * 16 + l16) * LDK + kk + quad * 8]; \
        _Pragma("unroll")                                                     \
        for (int j = 0; j < 4; j++) {                                         \
            int row = wn * 64 + j * 16 + l16;                                 \
            int c8L = quad + (kk >> 3);                                       \
            bfr[j] = *(const bf16x8*)&Bb[BB][row * 64 + ((c8L ^ (row & 7)) * 8)]; \
        }                                                                     \
        _Pragma("unroll")                                                     \
        for (int i = 0; i < 2; i++)                                           \
            _Pragma("unroll")                                                 \
            for (int j = 0; j < 4; j++)                                       \
                acc[i][j] = mfma16(af[i], bfr[j], acc[i][j]);                 \
    }

#define ITER(S, KQ, G0, G1)                                                   \
    {                                                                         \
        WRITE_A((S + 1) & 1, G0, G1);                                         \
        int kq2 = (KQ) + 128; if (kq2 > 4096) kq2 = 4096;                     \
        DMA_B((S + 2) & 3, kq2);                                              \
        __builtin_amdgcn_sched_barrier(0);                                    \
        GATHER((KQ) + 192, G0, G1);                                           \
        __builtin_amdgcn_sched_barrier(0);                                    \
        COMPUTE(S & 1, S);                                                    \
        asm volatile("s_waitcnt vmcnt(8) lgkmcnt(0)" ::: "memory");           \
        __builtin_amdgcn_s_barrier();                                         \
        __builtin_amdgcn_sched_barrier(0);                                    \
    }

__global__ __launch_bounds__(512, 2) void first_gemm_kernel(
    const u16* __restrict__ BT, const float* __restrict__ bfirst,
    const float* __restrict__ Pm,
    float* __restrict__ outF,
    const int* __restrict__ cidx, const float* __restrict__ cemb,
    const float* __restrict__ xnum)
{
    __shared__ __align__(16) u16 Ab[2][FBM * LDK];    // 2 x  9216 B
    __shared__ __align__(16) u16 Bb[4][256 * 64];     // 4 x 32768 B, swizzled no-pad
    __shared__ int   sidx[FBM * 16];                  //  4096 B
    __shared__ float sx[FBM * 32];                    //  8192 B  -> 161792 B total

    const int tid  = threadIdx.x;
    const int lane = tid & 63;
    const int wv   = tid >> 6;        // 0..7
    const int wm   = wv >> 2;         // 0..1 row half
    const int wn   = wv & 3;          // 0..3 col quarter
    const int quad = lane >> 4;
    const int l16  = lane & 15;
    const int m0   = blockIdx.x * FBM;

    sidx[tid]       = cidx[m0 * 16 + tid];
    sidx[tid + 512] = cidx[m0 * 16 + tid + 512];
    {
        float4 v = *(const float4*)&xnum[(size_t)m0 * 32 + tid * 4];
        *(float4*)&sx[tid * 4] = v;
    }
    __syncthreads();

    f32x4 acc[2][4];
#pragma unroll
    for (int i = 0; i < 2; i++)
#pragma unroll
        for (int j = 0; j < 4; j++) acc[i][j] = (f32x4){0.f, 0.f, 0.f, 0.f};

    float4 ga0, ga1, pa0, pa1, pb0, pb1;

    GATHER(0, ga0, ga1);
    WRITE_A(0, ga0, ga1);
    DMA_B(0, 0);
    __builtin_amdgcn_sched_barrier(0);
    GATHER(64, pa0, pa1);
    __builtin_amdgcn_sched_barrier(0);
    DMA_B(1, 64);
    __builtin_amdgcn_sched_barrier(0);
    GATHER(128, pb0, pb1);
    __builtin_amdgcn_sched_barrier(0);
    asm volatile("s_waitcnt vmcnt(8) lgkmcnt(0)" ::: "memory");
    __builtin_amdgcn_s_barrier();
    __builtin_amdgcn_sched_barrier(0);

#pragma unroll 1
    for (int k0 = 0; k0 < 4096; k0 += 256) {
        ITER(0, k0 +   0, pa0, pa1);
        ITER(1, k0 +  64, pb0, pb1);
        ITER(2, k0 + 128, pa0, pa1);
        ITER(3, k0 + 192, pb0, pb1);
    }
    COMPUTE(0, 0);   // k0 = 4096 (numeric/U tail)

    // bias folded here: c0[col] = b_first[col] + sum_f P[f][col]  (P is L2-hot)
    float bsv[4];
#pragma unroll
    for (int j = 0; j < 4; j++) {
        int col = wn * 64 + j * 16 + l16;
        float bs = bfirst[col];
#pragma unroll 8
        for (int f = 0; f < 32; f++) bs += Pm[f * 256 + col];
        bsv[j] = bs;
    }
#pragma unroll
    for (int i = 0; i < 2; i++) {
#pragma unroll
        for (int j = 0; j < 4; j++) {
            int col = wn * 64 + j * 16 + l16;
#pragma unroll
            for (int r = 0; r < 4; r++) {
                int row = m0 + wm * 32 + i * 16 + quad * 4 + r;
                outF[(size_t)row * 256 + col] = acc[i][j][r] + bsv[j];
            }
        }
    }
}

// ---------------- fused 8-layer residual stack + final LN + head ----------------
// v5: 32-row tile, 256 threads (4 waves), grid 512 = 2 blocks/CU. The stack is
// latency-bound (R4: MfmaUtil 13.8, VALU 15.4, HBM 3% — all idle): with one
// block/CU every barrier drain stalls the whole CU. Two independent barrier
// domains per CU interleave phases: block A's weight-load latency hides under
// block B's MFMAs. Phase code = R2's proven version (strides 264/520, plain
// __syncthreads, in-loop weight loads; NO register weight arrays - R3 spilled).
__global__ __launch_bounds__(256, 2) void stack_kernel(
    const float* __restrict__ h,
    const float* __restrict__ ln_g, const float* __restrict__ ln_b,
    const u16* __restrict__ W1T, const float* __restrict__ b1s,
    const u16* __restrict__ W2T, const float* __restrict__ b2s,
    const float* __restrict__ g_f, const float* __restrict__ beta_f,
    const float* __restrict__ Wh, const float* __restrict__ bh,
    float* __restrict__ out)
{
    __shared__ __align__(16) float hbuf[32 * 260];     // 33280 B, f32 h tile
    __shared__ __align__(16) u16   scratch[32 * 520];  // 33280 B, hn/hid union
    const int tid  = threadIdx.x;
    const int lane = tid & 63;
    const int wv   = tid >> 6;        // 0..3
    const int quad = lane >> 4;
    const int l16  = lane & 15;
    const int m0   = blockIdx.x * 32;

    // ---- load h tile (coalesced float4), wave per row, 8 rounds ----
#pragma unroll
    for (int rr = 0; rr < 8; rr++) {
        int row = rr * 4 + wv;
        *(float4*)&hbuf[row * 260 + lane * 4] =
            *(const float4*)&h[(size_t)(m0 + row) * 256 + lane * 4];
    }
    __syncthreads();

#pragma unroll 1
    for (int l = 0; l < 8; l++) {
        const u16* W1 = W1T + l * 131072;
        const u16* W2 = W2T + l * 131072;
        const float* bb1 = b1s + l * 512;
        const float* bb2 = b2s + l * 256;

        // ---- LN: wave per row, 8 rounds ----
        float4 gv4 = *(const float4*)&ln_g[l * 256 + lane * 4];
        float4 bv4 = *(const float4*)&ln_b[l * 256 + lane * 4];
#pragma unroll
        for (int rr = 0; rr < 8; rr++) {
            int row = rr * 4 + wv;
            float4 x = *(const float4*)&hbuf[row * 260 + lane * 4];
            float s  = x.x + x.y + x.z + x.w;
            float s2 = x.x * x.x + x.y * x.y + x.z * x.z + x.w * x.w;
#pragma unroll
            for (int o = 32; o > 0; o >>= 1) { s += __shfl_xor(s, o); s2 += __shfl_xor(s2, o); }
            float mu = s * (1.f / 256.f);
            float rs = rsqrtf(s2 * (1.f / 256.f) - mu * mu + 1e-5f);
            ushort4 o4;
            o4.x = f2bf((x.x - mu) * rs * gv4.x + bv4.x);
            o4.y = f2bf((x.y - mu) * rs * gv4.y + bv4.y);
            o4.z = f2bf((x.z - mu) * rs * gv4.z + bv4.z);
            o4.w = f2bf((x.w - mu) * rs * gv4.w + bv4.w);
            *(ushort4*)&scratch[row * 264 + lane * 4] = o4;
        }
        __syncthreads();

        // ---- FC1: wave owns cols [wv*128, +128), all 32 rows ----
        float b1v[8];
#pragma unroll
        for (int j = 0; j < 8; j++) b1v[j] = bb1[wv * 128 + j * 16 + l16];
        f32x4 acc1[2][8];
#pragma unroll
        for (int i = 0; i < 2; i++)
#pragma unroll
            for (int j = 0; j < 8; j++) acc1[i][j] = (f32x4){0.f, 0.f, 0.f, 0.f};
#pragma unroll
        for (int kk = 0; kk < 256; kk += 32) {
            bf16x8 af[2], bw[8];
#pragma unroll
            for (int i = 0; i < 2; i++)
                af[i] = *(const bf16x8*)&scratch[(i * 16 + l16) * 264 + kk + quad * 8];
#pragma unroll
            for (int j = 0; j < 8; j++)
                bw[j] = *(const bf16x8*)&W1[(size_t)(wv * 128 + j * 16 + l16) * 256 + kk + quad * 8];
#pragma unroll
            for (int i = 0; i < 2; i++)
#pragma unroll
                for (int j = 0; j < 8; j++)
                    acc1[i][j] = mfma16(af[i], bw[j], acc1[i][j]);
        }
        __syncthreads();   // all hn reads done before scratch reused as hid

        // ---- FC1 epilogue: relu -> hid (stride 520) ----
#pragma unroll
        for (int i = 0; i < 2; i++)
#pragma unroll
            for (int j = 0; j < 8; j++)
#pragma unroll
                for (int r = 0; r < 4; r++) {
                    float v = acc1[i][j][r] + b1v[j];
                    v = v > 0.f ? v : 0.f;
                    scratch[(i * 16 + quad * 4 + r) * 520 + wv * 128 + j * 16 + l16] = f2bf(v);
                }
        __syncthreads();

        // ---- FC2: wave owns cols [wv*64, +64), all 32 rows ----
        float b2v[4];
#pragma unroll
        for (int j = 0; j < 4; j++) b2v[j] = bb2[wv * 64 + j * 16 + l16];
        f32x4 acc2[2][4];
#pragma unroll
        for (int i = 0; i < 2; i++)
#pragma unroll
            for (int j = 0; j < 4; j++) acc2[i][j] = (f32x4){0.f, 0.f, 0.f, 0.f};
#pragma unroll
        for (int kk = 0; kk < 512; kk += 32) {
            bf16x8 af[2], bw[4];
#pragma unroll
            for (int i = 0; i < 2; i++)
                af[i] = *(const bf16x8*)&scratch[(i * 16 + l16) * 520 + kk + quad * 8];
#pragma unroll
            for (int j = 0; j < 4; j++)
                bw[j] = *(const bf16x8*)&W2[(size_t)(wv * 64 + j * 16 + l16) * 512 + kk + quad * 8];
#pragma unroll
            for (int i = 0; i < 2; i++)
#pragma unroll
                for (int j = 0; j < 4; j++)
                    acc2[i][j] = mfma16(af[i], bw[j], acc2[i][j]);
        }

        // ---- residual update in LDS (each element owned by one thread) ----
#pragma unroll
        for (int i = 0; i < 2; i++)
#pragma unroll
            for (int j = 0; j < 4; j++) {
                int col = wv * 64 + j * 16 + l16;
#pragma unroll
                for (int r = 0; r < 4; r++)
                    hbuf[(i * 16 + quad * 4 + r) * 260 + col] += acc2[i][j][r] + b2v[j];
            }
        __syncthreads();   // update + all hid reads done before next layer
    }

    // ---- final LN + [256 x 2] head, wave per row ----
    {
        float4 gv4 = *(const float4*)&g_f[lane * 4];
        float4 bv4 = *(const float4*)&beta_f[lane * 4];
        float4 wa = *(const float4*)&Wh[lane * 8];
        float4 wb = *(const float4*)&Wh[lane * 8 + 4];
        float bh0 = bh[0], bh1 = bh[1];
#pragma unroll
        for (int rr = 0; rr < 8; rr++) {
            int row = rr * 4 + wv;
            float4 x = *(const float4*)&hbuf[row * 260 + lane * 4];
            float s = x.x + x.y + x.z + x.w;
            float s2 = x.x * x.x + x.y * x.y + x.z * x.z + x.w * x.w;
#pragma unroll
            for (int o = 32; o > 0; o >>= 1) { s += __shfl_xor(s, o); s2 += __shfl_xor(s2, o); }
            float mu = s * (1.f / 256.f);
            float rs = rsqrtf(s2 * (1.f / 256.f) - mu * mu + 1e-5f);
            float xn0 = (x.x - mu) * rs * gv4.x + bv4.x;
            float xn1 = (x.y - mu) * rs * gv4.y + bv4.y;
            float xn2 = (x.z - mu) * rs * gv4.z + bv4.z;
            float xn3 = (x.w - mu) * rs * gv4.w + bv4.w;
            float d0 = xn0 * wa.x + xn1 * wa.z + xn2 * wb.x + xn3 * wb.z;
            float d1 = xn0 * wa.y + xn1 * wa.w + xn2 * wb.y + xn3 * wb.w;
#pragma unroll
            for (int o = 32; o > 0; o >>= 1) { d0 += __shfl_xor(d0, o); d1 += __shfl_xor(d1, o); }
            if (lane == 0) {
                out[(size_t)(m0 + row) * 2 + 0] = d0 + bh0;
                out[(size_t)(m0 + row) * 2 + 1] = d1 + bh1;
            }
        }
    }
}

// ---------------- launch ----------------
extern "C" void kernel_launch(void* const* d_in, const int* in_sizes, int n_in,
                              void* d_out, int out_size, void* d_ws, size_t ws_size,
                              hipStream_t stream)
{
    const float* x_num   = (const float*)d_in[0];
    const int*   cidx    = (const int*)d_in[1];
    const float* w_num   = (const float*)d_in[2];
    const float* b_num   = (const float*)d_in[3];
    const float* cemb    = (const float*)d_in[4];
    const float* W_first = (const float*)d_in[5];
    const float* b_first = (const float*)d_in[6];
    const float* ln_g    = (const float*)d_in[7];
    const float* ln_b    = (const float*)d_in[8];
    const float* W1s     = (const float*)d_in[9];
    const float* b1s     = (const float*)d_in[10];
    const float* W2s     = (const float*)d_in[11];
    const float* b2s     = (const float*)d_in[12];
    const float* g_f     = (const float*)d_in[13];
    const float* beta_f  = (const float*)d_in[14];
    const float* W_head  = (const float*)d_in[15];
    const float* b_head  = (const float*)d_in[16];
    float* out = (float*)d_out;

    char* ws = (char*)d_ws;
    float* U   = (float*)(ws + 0);          //  32 KB
    float* P   = (float*)(ws + 33792);      //  32 KB
    u16* WcT   = (u16*)(ws + 66560);        // 256 x 4160 bf16
    u16* W1T   = (u16*)(ws + 2196480);      // 8 x 512 x 256 bf16
    u16* W2T   = (u16*)(ws + 4293632);      // 8 x 256 x 512 bf16
    float* h   = (float*)(ws + 6390784);    // 16384 x 256 f32
    // prep partials alias the W1T region (consumed before W1T is written)
    float* Upart = (float*)(ws + 2196480);  // 256 KB
    float* Ppart = (float*)(ws + 2458624);  // 256 KB

    prep_u_kernel<<<dim3(32, 8), 256, 0, stream>>>(w_num, b_num, W_first, Upart, Ppart);
    prep_reduce_kernel<<<32, 256, 0, stream>>>(Upart, Ppart, U, P);
    transpose_kernel<<<dim3(64, 4, 1), 256, 0, stream>>>(
        W_first + (size_t)8192 * 256, WcT, 4096, 256, 4160, 0, 0, 0);
    transpose_kernel<<<dim3(1, 4, 1), 256, 0, stream>>>(
        U, WcT, 32, 256, 4160, 4096, 0, 0);
    transpose_kernel<<<dim3(4, 8, 8), 256, 0, stream>>>(
        W1s, W1T, 256, 512, 256, 0, 131072, 131072);
    transpose_kernel<<<dim3(8, 4, 8), 256, 0, stream>>>(
        W2s, W2T, 512, 256, 512, 0, 131072, 131072);

    first_gemm_kernel<<<256, 512, 0, stream>>>(
        WcT, b_first, P, h, cidx, cemb, x_num);

    stack_kernel<<<512, 256, 0, stream>>>(
        h, ln_g, ln_b, W1T, b1s, W2T, b2s,
        g_f, beta_f, W_head, b_head, out);
}

// Round 7
// 434.075 us; speedup vs baseline: 1.3869x; 1.3869x over previous
//
#include <hip/hip_runtime.h>

typedef unsigned short u16;
typedef unsigned int u32;
typedef __attribute__((ext_vector_type(8))) short bf16x8;
typedef __attribute__((ext_vector_type(4))) float f32x4;

#define LDK 72   // A-tile LDS stride (64 + 8 pad)

__device__ __forceinline__ u16 f2bf(float f) {
    u32 u = __float_as_uint(f);
    u += 0x7fffu + ((u >> 16) & 1u);   // round-to-nearest-even
    return (u16)(u >> 16);
}

__device__ __forceinline__ f32x4 mfma16(bf16x8 a, bf16x8 b, f32x4 c) {
    return __builtin_amdgcn_mfma_f32_16x16x32_bf16(a, b, c, 0, 0, 0);
}

// ---------------- prep: fold numeric features (split-k x8) ----------------

__global__ __launch_bounds__(256) void prep_u_kernel(
    const float* __restrict__ w_num, const float* __restrict__ b_num,
    const float* __restrict__ W_first, float* __restrict__ Upart, float* __restrict__ Ppart)
{
    __shared__ float wrow[32];
    __shared__ float brow[32];
    int j = threadIdx.x, f = blockIdx.x, ks = blockIdx.y;
    if (j < 32) {
        wrow[j] = w_num[f * 256 + ks * 32 + j];
        brow[j] = b_num[f * 256 + ks * 32 + j];
    }
    __syncthreads();
    float au = 0.f, ap = 0.f;
#pragma unroll 8
    for (int k = 0; k < 32; k++) {
        float w = W_first[(size_t)((f << 8) + ks * 32 + k) * 256 + j];
        au = fmaf(wrow[k], w, au);
        ap = fmaf(brow[k], w, ap);
    }
    Upart[(size_t)(ks * 32 + f) * 256 + j] = au;
    Ppart[(size_t)(ks * 32 + f) * 256 + j] = ap;
}

// reduce partials; write U directly into WcT (bf16, transposed) + P (f32)
__global__ __launch_bounds__(256) void prep_reduce_kernel(
    const float* __restrict__ Upart, const float* __restrict__ Ppart,
    u16* __restrict__ WcT, float* __restrict__ P)
{
    int j = threadIdx.x, f = blockIdx.x;
    float au = 0.f, ap = 0.f;
#pragma unroll
    for (int ks = 0; ks < 8; ks++) {
        au += Upart[(size_t)(ks * 32 + f) * 256 + j];
        ap += Ppart[(size_t)(ks * 32 + f) * 256 + j];
    }
    WcT[(size_t)j * 4160 + 4096 + f] = f2bf(au);
    P[f * 256 + j] = ap;
}

// ---------------- prep: LDS-tiled transpose f32 -> bf16 ----------------
__global__ __launch_bounds__(256) void transpose_kernel(
    const float* __restrict__ in, u16* __restrict__ out,
    int R, int C, int ldo, int k_off, size_t in_stride, size_t out_stride)
{
    __shared__ float t[64][65];
    in  += (size_t)blockIdx.z * in_stride;
    out += (size_t)blockIdx.z * out_stride;
    const int tid = threadIdx.x;
    const int r0 = blockIdx.x * 64, c0 = blockIdx.y * 64;
#pragma unroll
    for (int i = 0; i < 16; i++) {
        int e = tid + i * 256;
        int r = e >> 6, c = e & 63;
        float v = (r0 + r < R) ? in[(size_t)(r0 + r) * C + c0 + c] : 0.f;
        t[c][r] = v;
    }
    __syncthreads();
#pragma unroll
    for (int i = 0; i < 2; i++) {
        int e = tid + i * 256;
        int c = e >> 3, r8 = (e & 7) * 8;
        u16 tmp[8];
#pragma unroll
        for (int x = 0; x < 8; x++) tmp[x] = f2bf(t[c][r8 + x]);
        *(bf16x8*)&out[(size_t)(c0 + c) * ldo + k_off + r0 + r8] = *(bf16x8*)tmp;
    }
}

// ---------------- first layer: gathered-A GEMM (unchanged) ----------------
#define FBM 64

#define GATHER(KQ, G0, G1)                                                    \
    {                                                                         \
        int chunk = tid;                                                      \
        int r = chunk >> 4, c4 = chunk & 15;                                  \
        int k = (KQ) + c4 * 4;                                                \
        int rowi = (k < 4096) ? sidx[r * 16 + ((k >> 8) & 15)] : 0;           \
        G0 = *(const float4*)&cemb[(size_t)rowi * 256 + (k & 255)];           \
        if (k >= 4096) {                                                      \
            if (k < 4128) {                                                   \
                int c = r * 32 + (k - 4096);                                  \
                G0.x = sx[c]; G0.y = sx[c + 1];                               \
                G0.z = sx[c + 2]; G0.w = sx[c + 3];                           \
            } else G0 = make_float4(0.f, 0.f, 0.f, 0.f);                      \
        }                                                                     \
        chunk = tid + 512;                                                    \
        r = chunk >> 4; c4 = chunk & 15;                                      \
        k = (KQ) + c4 * 4;                                                    \
        rowi = (k < 4096) ? sidx[r * 16 + ((k >> 8) & 15)] : 0;               \
        G1 = *(const float4*)&cemb[(size_t)rowi * 256 + (k & 255)];           \
        if (k >= 4096) {                                                      \
            if (k < 4128) {                                                   \
                int c = r * 32 + (k - 4096);                                  \
                G1.x = sx[c]; G1.y = sx[c + 1];                               \
                G1.z = sx[c + 2]; G1.w = sx[c + 3];                           \
            } else G1 = make_float4(0.f, 0.f, 0.f, 0.f);                      \
        }                                                                     \
    }

#define WRITE_A(BUF, G0, G1)                                                  \
    {                                                                         \
        int chunk = tid;                                                      \
        int r = chunk >> 4, c4 = chunk & 15;                                  \
        ushort4 o;                                                            \
        o.x = f2bf(G0.x); o.y = f2bf(G0.y); o.z = f2bf(G0.z); o.w = f2bf(G0.w); \
        *(ushort4*)&Ab[BUF][r * LDK + c4 * 4] = o;                            \
        chunk = tid + 512;                                                    \
        r = chunk >> 4; c4 = chunk & 15;                                      \
        o.x = f2bf(G1.x); o.y = f2bf(G1.y); o.z = f2bf(G1.z); o.w = f2bf(G1.w); \
        *(ushort4*)&Ab[BUF][r * LDK + c4 * 4] = o;                            \
    }

#define DMA_B(BUF, KQ)                                                        \
    _Pragma("unroll")                                                         \
    for (int it = 0; it < 4; it++) {                                          \
        int chunk = it * 512 + tid;                                           \
        int r = chunk >> 3;                                                   \
        int c8 = (chunk & 7) ^ (r & 7);                                       \
        const u16* src = &BT[(size_t)r * 4160 + (KQ) + c8 * 8];               \
        __builtin_amdgcn_global_load_lds(                                     \
            (const __attribute__((address_space(1))) void*)src,               \
            (__attribute__((address_space(3))) void*)&Bb[BUF][(it * 512 + wv * 64) * 8], \
            16, 0, 0);                                                        \
    }

#define COMPUTE(AB, BB)                                                       \
    _Pragma("unroll")                                                         \
    for (int kk = 0; kk < 64; kk += 32) {                                     \
        bf16x8 af[2], bfr[4];                                                 \
        _Pragma("unroll")                                                     \
        for (int i = 0; i < 2; i++)                                           \
            af[i] = *(const bf16x8*)&Ab[AB][(wm * 32 + i * 16 + l16) * LDK + kk + quad * 8]; \
        _Pragma("unroll")                                                     \
        for (int j = 0; j < 4; j++) {                                         \
            int row = wn * 64 + j * 16 + l16;                                 \
            int c8L = quad + (kk >> 3);                                       \
            bfr[j] = *(const bf16x8*)&Bb[BB][row * 64 + ((c8L ^ (row & 7)) * 8)]; \
        }                                                                     \
        _Pragma("unroll")                                                     \
        for (int i = 0; i < 2; i++)                                           \
            _Pragma("unroll")                                                 \
            for (int j = 0; j < 4; j++)                                       \
                acc[i][j] = mfma16(af[i], bfr[j], acc[i][j]);                 \
    }

#define ITER(S, KQ, G0, G1)                                                   \
    {                                                                         \
        WRITE_A((S + 1) & 1, G0, G1);                                         \
        int kq2 = (KQ) + 128; if (kq2 > 4096) kq2 = 4096;                     \
        DMA_B((S + 2) & 3, kq2);                                              \
        __builtin_amdgcn_sched_barrier(0);                                    \
        GATHER((KQ) + 192, G0, G1);                                           \
        __builtin_amdgcn_sched_barrier(0);                                    \
        COMPUTE(S & 1, S);                                                    \
        asm volatile("s_waitcnt vmcnt(8) lgkmcnt(0)" ::: "memory");           \
        __builtin_amdgcn_s_barrier();                                         \
        __builtin_amdgcn_sched_barrier(0);                                    \
    }

__global__ __launch_bounds__(512, 2) void first_gemm_kernel(
    const u16* __restrict__ BT, const float* __restrict__ bfirst,
    const float* __restrict__ Pm,
    float* __restrict__ outF,
    const int* __restrict__ cidx, const float* __restrict__ cemb,
    const float* __restrict__ xnum)
{
    __shared__ __align__(16) u16 Ab[2][FBM * LDK];    // 2 x  9216 B
    __shared__ __align__(16) u16 Bb[4][256 * 64];     // 4 x 32768 B, swizzled no-pad
    __shared__ int   sidx[FBM * 16];                  //  4096 B
    __shared__ float sx[FBM * 32];                    //  8192 B  -> 161792 B total

    const int tid  = threadIdx.x;
    const int lane = tid & 63;
    const int wv   = tid >> 6;        // 0..7
    const int wm   = wv >> 2;         // 0..1 row half
    const int wn   = wv & 3;          // 0..3 col quarter
    const int quad = lane >> 4;
    const int l16  = lane & 15;
    const int m0   = blockIdx.x * FBM;

    sidx[tid]       = cidx[m0 * 16 + tid];
    sidx[tid + 512] = cidx[m0 * 16 + tid + 512];
    {
        float4 v = *(const float4*)&xnum[(size_t)m0 * 32 + tid * 4];
        *(float4*)&sx[tid * 4] = v;
    }
    __syncthreads();

    f32x4 acc[2][4];
#pragma unroll
    for (int i = 0; i < 2; i++)
#pragma unroll
        for (int j = 0; j < 4; j++) acc[i][j] = (f32x4){0.f, 0.f, 0.f, 0.f};

    float4 ga0, ga1, pa0, pa1, pb0, pb1;

    GATHER(0, ga0, ga1);
    WRITE_A(0, ga0, ga1);
    DMA_B(0, 0);
    __builtin_amdgcn_sched_barrier(0);
    GATHER(64, pa0, pa1);
    __builtin_amdgcn_sched_barrier(0);
    DMA_B(1, 64);
    __builtin_amdgcn_sched_barrier(0);
    GATHER(128, pb0, pb1);
    __builtin_amdgcn_sched_barrier(0);
    asm volatile("s_waitcnt vmcnt(8) lgkmcnt(0)" ::: "memory");
    __builtin_amdgcn_s_barrier();
    __builtin_amdgcn_sched_barrier(0);

#pragma unroll 1
    for (int k0 = 0; k0 < 4096; k0 += 256) {
        ITER(0, k0 +   0, pa0, pa1);
        ITER(1, k0 +  64, pb0, pb1);
        ITER(2, k0 + 128, pa0, pa1);
        ITER(3, k0 + 192, pb0, pb1);
    }
    COMPUTE(0, 0);   // k0 = 4096 (numeric/U tail)

    // bias folded here: c0[col] = b_first[col] + sum_f P[f][col]  (P is L2-hot)
    float bsv[4];
#pragma unroll
    for (int j = 0; j < 4; j++) {
        int col = wn * 64 + j * 16 + l16;
        float bs = bfirst[col];
#pragma unroll 8
        for (int f = 0; f < 32; f++) bs += Pm[f * 256 + col];
        bsv[j] = bs;
    }
#pragma unroll
    for (int i = 0; i < 2; i++) {
#pragma unroll
        for (int j = 0; j < 4; j++) {
            int col = wn * 64 + j * 16 + l16;
#pragma unroll
            for (int r = 0; r < 4; r++) {
                int row = m0 + wm * 32 + i * 16 + quad * 4 + r;
                outF[(size_t)row * 256 + col] = acc[i][j][r] + bsv[j];
            }
        }
    }
}

// ---------------- fused 8-layer residual stack + final LN + head ----------------
// v6b (R6 resubmit after infra failure): R2's proven 64-row / 1-block-per-CU
// structure (weight traffic fetched once per CU — R5's 2 blocks/CU doubled L2
// streams and thrashed to HBM, FETCH 32->160MB), with 1024 threads = 16 waves
// = 4 waves/SIMD. The stack is phase-latency-bound with all pipes idle;
// doubling waves/SIMD doubles the independent dependency chains hiding each
// LDS/L2 latency. Per-wave tiling halves (FC1: 32 cols, FC2: 16 cols, LN: 4
// rounds); per-block work, LDS (133KB), and weight traffic unchanged.
__global__ __launch_bounds__(1024) void stack_kernel(
    const float* __restrict__ h,
    const float* __restrict__ ln_g, const float* __restrict__ ln_b,
    const u16* __restrict__ W1T, const float* __restrict__ b1s,
    const u16* __restrict__ W2T, const float* __restrict__ b2s,
    const float* __restrict__ g_f, const float* __restrict__ beta_f,
    const float* __restrict__ Wh, const float* __restrict__ bh,
    float* __restrict__ out)
{
    __shared__ __align__(16) float hbuf[64 * 260];     // 66560 B, f32 h tile
    __shared__ __align__(16) u16   scratch[64 * 520];  // 66560 B, hn/hid union
    const int tid  = threadIdx.x;
    const int lane = tid & 63;
    const int wv   = tid >> 6;        // 0..15
    const int quad = lane >> 4;
    const int l16  = lane & 15;
    const int m0   = blockIdx.x * 64;

    // ---- load h tile (coalesced float4), wave per row, 4 rounds ----
#pragma unroll
    for (int rr = 0; rr < 4; rr++) {
        int row = rr * 16 + wv;
        *(float4*)&hbuf[row * 260 + lane * 4] =
            *(const float4*)&h[(size_t)(m0 + row) * 256 + lane * 4];
    }
    __syncthreads();

#pragma unroll 1
    for (int l = 0; l < 8; l++) {
        const u16* W1 = W1T + l * 131072;
        const u16* W2 = W2T + l * 131072;
        const float* bb1 = b1s + l * 512;
        const float* bb2 = b2s + l * 256;

        // ---- LN: wave per row, 4 rounds ----
        float4 gv4 = *(const float4*)&ln_g[l * 256 + lane * 4];
        float4 bv4 = *(const float4*)&ln_b[l * 256 + lane * 4];
#pragma unroll
        for (int rr = 0; rr < 4; rr++) {
            int row = rr * 16 + wv;
            float4 x = *(const float4*)&hbuf[row * 260 + lane * 4];
            float s  = x.x + x.y + x.z + x.w;
            float s2 = x.x * x.x + x.y * x.y + x.z * x.z + x.w * x.w;
#pragma unroll
            for (int o = 32; o > 0; o >>= 1) { s += __shfl_xor(s, o); s2 += __shfl_xor(s2, o); }
            float mu = s * (1.f / 256.f);
            float rs = rsqrtf(s2 * (1.f / 256.f) - mu * mu + 1e-5f);
            ushort4 o4;
            o4.x = f2bf((x.x - mu) * rs * gv4.x + bv4.x);
            o4.y = f2bf((x.y - mu) * rs * gv4.y + bv4.y);
            o4.z = f2bf((x.z - mu) * rs * gv4.z + bv4.z);
            o4.w = f2bf((x.w - mu) * rs * gv4.w + bv4.w);
            *(ushort4*)&scratch[row * 264 + lane * 4] = o4;
        }
        __syncthreads();

        // ---- FC1: wave owns cols [wv*32, +32), all 64 rows ----
        float b1v[2];
#pragma unroll
        for (int j = 0; j < 2; j++) b1v[j] = bb1[wv * 32 + j * 16 + l16];
        f32x4 acc1[4][2];
#pragma unroll
        for (int i = 0; i < 4; i++)
#pragma unroll
            for (int j = 0; j < 2; j++) acc1[i][j] = (f32x4){0.f, 0.f, 0.f, 0.f};
#pragma unroll
        for (int kk = 0; kk < 256; kk += 32) {
            bf16x8 af[4], bw[2];
#pragma unroll
            for (int i = 0; i < 4; i++)
                af[i] = *(const bf16x8*)&scratch[(i * 16 + l16) * 264 + kk + quad * 8];
#pragma unroll
            for (int j = 0; j < 2; j++)
                bw[j] = *(const bf16x8*)&W1[(size_t)(wv * 32 + j * 16 + l16) * 256 + kk + quad * 8];
#pragma unroll
            for (int i = 0; i < 4; i++)
#pragma unroll
                for (int j = 0; j < 2; j++)
                    acc1[i][j] = mfma16(af[i], bw[j], acc1[i][j]);
        }
        __syncthreads();   // all hn reads done before scratch reused as hid

        // ---- FC1 epilogue: relu -> hid (stride 520) ----
#pragma unroll
        for (int i = 0; i < 4; i++)
#pragma unroll
            for (int j = 0; j < 2; j++)
#pragma unroll
                for (int r = 0; r < 4; r++) {
                    float v = acc1[i][j][r] + b1v[j];
                    v = v > 0.f ? v : 0.f;
                    scratch[(i * 16 + quad * 4 + r) * 520 + wv * 32 + j * 16 + l16] = f2bf(v);
                }
        __syncthreads();

        // ---- FC2: wave owns cols [wv*16, +16), all 64 rows ----
        float b2v = bb2[wv * 16 + l16];
        f32x4 acc2[4];
#pragma unroll
        for (int i = 0; i < 4; i++) acc2[i] = (f32x4){0.f, 0.f, 0.f, 0.f};
#pragma unroll
        for (int kk = 0; kk < 512; kk += 32) {
            bf16x8 af[4], bw;
#pragma unroll
            for (int i = 0; i < 4; i++)
                af[i] = *(const bf16x8*)&scratch[(i * 16 + l16) * 520 + kk + quad * 8];
            bw = *(const bf16x8*)&W2[(size_t)(wv * 16 + l16) * 512 + kk + quad * 8];
#pragma unroll
            for (int i = 0; i < 4; i++)
                acc2[i] = mfma16(af[i], bw, acc2[i]);
        }

        // ---- residual update in LDS (each element owned by one thread) ----
#pragma unroll
        for (int i = 0; i < 4; i++) {
            int col = wv * 16 + l16;
#pragma unroll
            for (int r = 0; r < 4; r++)
                hbuf[(i * 16 + quad * 4 + r) * 260 + col] += acc2[i][r] + b2v;
        }
        __syncthreads();   // update + all hid reads done before next layer
    }

    // ---- final LN + [256 x 2] head, wave per row ----
    {
        float4 gv4 = *(const float4*)&g_f[lane * 4];
        float4 bv4 = *(const float4*)&beta_f[lane * 4];
        float4 wa = *(const float4*)&Wh[lane * 8];
        float4 wb = *(const float4*)&Wh[lane * 8 + 4];
        float bh0 = bh[0], bh1 = bh[1];
#pragma unroll
        for (int rr = 0; rr < 4; rr++) {
            int row = rr * 16 + wv;
            float4 x = *(const float4*)&hbuf[row * 260 + lane * 4];
            float s = x.x + x.y + x.z + x.w;
            float s2 = x.x * x.x + x.y * x.y + x.z * x.z + x.w * x.w;
#pragma unroll
            for (int o = 32; o > 0; o >>= 1) { s += __shfl_xor(s, o); s2 += __shfl_xor(s2, o); }
            float mu = s * (1.f / 256.f);
            float rs = rsqrtf(s2 * (1.f / 256.f) - mu * mu + 1e-5f);
            float xn0 = (x.x - mu) * rs * gv4.x + bv4.x;
            float xn1 = (x.y - mu) * rs * gv4.y + bv4.y;
            float xn2 = (x.z - mu) * rs * gv4.z + bv4.z;
            float xn3 = (x.w - mu) * rs * gv4.w + bv4.w;
            float d0 = xn0 * wa.x + xn1 * wa.z + xn2 * wb.x + xn3 * wb.z;
            float d1 = xn0 * wa.y + xn1 * wa.w + xn2 * wb.y + xn3 * wb.w;
#pragma unroll
            for (int o = 32; o > 0; o >>= 1) { d0 += __shfl_xor(d0, o); d1 += __shfl_xor(d1, o); }
            if (lane == 0) {
                out[(size_t)(m0 + row) * 2 + 0] = d0 + bh0;
                out[(size_t)(m0 + row) * 2 + 1] = d1 + bh1;
            }
        }
    }
}

// ---------------- launch ----------------
extern "C" void kernel_launch(void* const* d_in, const int* in_sizes, int n_in,
                              void* d_out, int out_size, void* d_ws, size_t ws_size,
                              hipStream_t stream)
{
    const float* x_num   = (const float*)d_in[0];
    const int*   cidx    = (const int*)d_in[1];
    const float* w_num   = (const float*)d_in[2];
    const float* b_num   = (const float*)d_in[3];
    const float* cemb    = (const float*)d_in[4];
    const float* W_first = (const float*)d_in[5];
    const float* b_first = (const float*)d_in[6];
    const float* ln_g    = (const float*)d_in[7];
    const float* ln_b    = (const float*)d_in[8];
    const float* W1s     = (const float*)d_in[9];
    const float* b1s     = (const float*)d_in[10];
    const float* W2s     = (const float*)d_in[11];
    const float* b2s     = (const float*)d_in[12];
    const float* g_f     = (const float*)d_in[13];
    const float* beta_f  = (const float*)d_in[14];
    const float* W_head  = (const float*)d_in[15];
    const float* b_head  = (const float*)d_in[16];
    float* out = (float*)d_out;

    char* ws = (char*)d_ws;
    float* P   = (float*)(ws + 33792);      //  32 KB
    u16* WcT   = (u16*)(ws + 66560);        // 256 x 4160 bf16
    u16* W1T   = (u16*)(ws + 2196480);      // 8 x 512 x 256 bf16
    u16* W2T   = (u16*)(ws + 4293632);      // 8 x 256 x 512 bf16
    float* h   = (float*)(ws + 6390784);    // 16384 x 256 f32
    // prep partials alias the W1T region (consumed before W1T is written)
    float* Upart = (float*)(ws + 2196480);  // 256 KB
    float* Ppart = (float*)(ws + 2458624);  // 256 KB

    prep_u_kernel<<<dim3(32, 8), 256, 0, stream>>>(w_num, b_num, W_first, Upart, Ppart);
    transpose_kernel<<<dim3(64, 4, 1), 256, 0, stream>>>(
        W_first + (size_t)8192 * 256, WcT, 4096, 256, 4160, 0, 0, 0);
    prep_reduce_kernel<<<32, 256, 0, stream>>>(Upart, Ppart, WcT, P);
    transpose_kernel<<<dim3(4, 8, 8), 256, 0, stream>>>(
        W1s, W1T, 256, 512, 256, 0, 131072, 131072);
    transpose_kernel<<<dim3(8, 4, 8), 256, 0, stream>>>(
        W2s, W2T, 512, 256, 512, 0, 131072, 131072);

    first_gemm_kernel<<<256, 512, 0, stream>>>(
        WcT, b_first, P, h, cidx, cemb, x_num);

    stack_kernel<<<256, 1024, 0, stream>>>(
        h, ln_g, ln_b, W1T, b1s, W2T, b2s,
        g_f, beta_f, W_head, b_head, out);
}